// Round 1
// baseline (395.146 us; speedup 1.0000x reference)
//
#include <hip/hip_runtime.h>

#define GAMMA 0.1f
#define EPS_F 1e-12f

// out[i] = -gamma * v[i]   (float2 per thread; out later accumulated by atomics)
__global__ void init_out_kernel(const float2* __restrict__ v,
                                float2* __restrict__ out, int n) {
    int i = blockIdx.x * blockDim.x + threadIdx.x;
    if (i < n) {
        float2 vi = v[i];
        out[i] = make_float2(-GAMMA * vi.x, -GAMMA * vi.y);
    }
}

__device__ __forceinline__ void do_edge(const float2* __restrict__ x,
                                        int s, int d,
                                        float* __restrict__ out) {
    float2 xs = x[s];
    float2 xd = x[d];
    float dx = xd.x - xs.x;
    float dy = xd.y - xs.y;
    float r = sqrtf(dx * dx + dy * dy);
    // m = -C*P*(r - r_c) * dr / max(r, eps);  C=1, P=2, r_c=1
    float scale = -2.0f * (r - 1.0f) / fmaxf(r, EPS_F);
    atomicAdd(&out[2 * d], scale * dx);
    atomicAdd(&out[2 * d + 1], scale * dy);
}

// One lane per 4 edges: int4 index loads (16B/lane coalescing), float2 gathers,
// 2 f32 atomics per edge into out.
__global__ void edge_kernel(const float2* __restrict__ x,
                            const int4* __restrict__ src4,
                            const int4* __restrict__ dst4,
                            const int* __restrict__ src,
                            const int* __restrict__ dst,
                            float* __restrict__ out,
                            int e4, int e_total) {
    int i = blockIdx.x * blockDim.x + threadIdx.x;
    if (i < e4) {
        int4 s = src4[i];
        int4 d = dst4[i];
        do_edge(x, s.x, d.x, out);
        do_edge(x, s.y, d.y, out);
        do_edge(x, s.z, d.z, out);
        do_edge(x, s.w, d.w, out);
    }
    // tail (E % 4 edges) handled by global thread 0
    if (i == 0) {
        for (int e = e4 * 4; e < e_total; ++e) {
            do_edge(x, src[e], dst[e], out);
        }
    }
}

extern "C" void kernel_launch(void* const* d_in, const int* in_sizes, int n_in,
                              void* d_out, int out_size, void* d_ws, size_t ws_size,
                              hipStream_t stream) {
    const float2* x = (const float2*)d_in[0];   // [N,2] fp32
    const float2* v = (const float2*)d_in[1];   // [N,2] fp32
    const int* src  = (const int*)d_in[2];      // [E] int32
    const int* dst  = (const int*)d_in[3];      // [E] int32

    int n = in_sizes[0] / 2;   // N nodes
    int e = in_sizes[2];       // E edges
    int e4 = e / 4;

    float* out = (float*)d_out;

    // 1) out = -gamma * v  (must run before atomics; same-stream ordering)
    {
        int threads = 256;
        int blocks = (n + threads - 1) / threads;
        init_out_kernel<<<blocks, threads, 0, stream>>>(v, (float2*)out, n);
    }

    // 2) scatter-add spring messages
    {
        int threads = 256;
        int blocks = (e4 + threads - 1) / threads;
        if (blocks < 1) blocks = 1;
        edge_kernel<<<blocks, threads, 0, stream>>>(
            x, (const int4*)src, (const int4*)dst, src, dst, out, e4, e);
    }
}

// Round 2
// 133.589 us; speedup vs baseline: 2.9579x; 2.9579x over previous
//
#include <hip/hip_runtime.h>

#define GAMMA 0.1f
#define EPS_F 1e-12f

// ---- partition-scan configuration ----
// 20000 nodes/partition * sizeof(float2) = 160000 B LDS (gfx950 has 160 KiB/CU)
#define S_NODES 20000
#define SCAN_THREADS 1024
#define B_TARGET 51   // chunks per partition; P=5 -> grid 255 blocks (~1/CU)

// process one edge into the LDS accumulator if dst falls in [lo,hi)
#define EDGE(dd, ss) do {                                        \
    int d_ = (dd);                                               \
    if (d_ >= lo && d_ < hi) {                                   \
        float2 xs = x[(ss)];                                     \
        float2 xd = x[d_];                                       \
        float dx = xd.x - xs.x;                                  \
        float dy = xd.y - xs.y;                                  \
        float r = sqrtf(dx * dx + dy * dy);                      \
        float sc = -2.0f * (r - 1.0f) / fmaxf(r, EPS_F);         \
        atomicAdd(&acc[d_ - lo].x, sc * dx);                     \
        atomicAdd(&acc[d_ - lo].y, sc * dy);                     \
    }                                                            \
} while (0)

__global__ __launch_bounds__(SCAN_THREADS, 1)
void scan_kernel(const float2* __restrict__ x,
                 const int4* __restrict__ src4,
                 const int4* __restrict__ dst4,
                 const int* __restrict__ src,
                 const int* __restrict__ dst,
                 float2* __restrict__ ws,
                 int e, int n, int B, int chunk) {
    __shared__ float2 acc[S_NODES];
    int p = blockIdx.x / B;
    int b = blockIdx.x - p * B;
    int lo = p * S_NODES;
    int hi = min(lo + S_NODES, n);
    int tid = threadIdx.x;

    for (int i = tid; i < S_NODES; i += SCAN_THREADS)
        acc[i] = make_float2(0.f, 0.f);
    __syncthreads();

    int estart = b * chunk;
    int eend = min(estart + chunk, e);
    if (estart < eend) {
        int nvec = (eend - estart) >> 2;           // int4 groups (estart is 4-aligned)
        const int4* d4p = dst4 + (estart >> 2);
        const int4* s4p = src4 + (estart >> 2);
        for (int i = tid; i < nvec; i += SCAN_THREADS) {
            int4 d4 = d4p[i];
            int4 s4 = s4p[i];
            EDGE(d4.x, s4.x);
            EDGE(d4.y, s4.y);
            EDGE(d4.z, s4.z);
            EDGE(d4.w, s4.w);
        }
        // scalar tail (only if chunk not multiple of 4 at the very end)
        for (int i = estart + (nvec << 2) + tid; i < eend; i += SCAN_THREADS)
            EDGE(dst[i], src[i]);
    }
    __syncthreads();

    // flush partition partial to workspace (plain coalesced stores)
    float2* wsb = ws + (size_t)blockIdx.x * S_NODES;
    for (int i = tid; i < S_NODES; i += SCAN_THREADS)
        wsb[i] = acc[i];
}

__global__ void reduce_kernel(const float2* __restrict__ ws,
                              const float2* __restrict__ v,
                              float2* __restrict__ out,
                              int n, int B) {
    int i = blockIdx.x * blockDim.x + threadIdx.x;
    if (i >= n) return;
    int p = i / S_NODES;
    int loc = i - p * S_NODES;
    const float2* base = ws + ((size_t)(p * B) * S_NODES + loc);
    float sx = 0.f, sy = 0.f;
    for (int b = 0; b < B; ++b) {
        float2 t = base[(size_t)b * S_NODES];
        sx += t.x;
        sy += t.y;
    }
    float2 vi = v[i];
    out[i] = make_float2(sx - GAMMA * vi.x, sy - GAMMA * vi.y);
}

// ---------- fallback path (global atomics) if ws too small ----------
__global__ void init_out_kernel(const float2* __restrict__ v,
                                float2* __restrict__ out, int n) {
    int i = blockIdx.x * blockDim.x + threadIdx.x;
    if (i < n) {
        float2 vi = v[i];
        out[i] = make_float2(-GAMMA * vi.x, -GAMMA * vi.y);
    }
}

__device__ __forceinline__ void do_edge_atomic(const float2* __restrict__ x,
                                               int s, int d,
                                               float* __restrict__ out) {
    float2 xs = x[s];
    float2 xd = x[d];
    float dx = xd.x - xs.x;
    float dy = xd.y - xs.y;
    float r = sqrtf(dx * dx + dy * dy);
    float sc = -2.0f * (r - 1.0f) / fmaxf(r, EPS_F);
    atomicAdd(&out[2 * d], sc * dx);
    atomicAdd(&out[2 * d + 1], sc * dy);
}

__global__ void edge_kernel_atomic(const float2* __restrict__ x,
                                   const int4* __restrict__ src4,
                                   const int4* __restrict__ dst4,
                                   const int* __restrict__ src,
                                   const int* __restrict__ dst,
                                   float* __restrict__ out,
                                   int e4, int e_total) {
    int i = blockIdx.x * blockDim.x + threadIdx.x;
    if (i < e4) {
        int4 s = src4[i];
        int4 d = dst4[i];
        do_edge_atomic(x, s.x, d.x, out);
        do_edge_atomic(x, s.y, d.y, out);
        do_edge_atomic(x, s.z, d.z, out);
        do_edge_atomic(x, s.w, d.w, out);
    }
    if (i == 0) {
        for (int e = e4 * 4; e < e_total; ++e)
            do_edge_atomic(x, src[e], dst[e], out);
    }
}

extern "C" void kernel_launch(void* const* d_in, const int* in_sizes, int n_in,
                              void* d_out, int out_size, void* d_ws, size_t ws_size,
                              hipStream_t stream) {
    const float2* x = (const float2*)d_in[0];   // [N,2] fp32
    const float2* v = (const float2*)d_in[1];   // [N,2] fp32
    const int* src  = (const int*)d_in[2];      // [E] int32
    const int* dst  = (const int*)d_in[3];      // [E] int32

    int n = in_sizes[0] / 2;   // N nodes
    int e = in_sizes[2];       // E edges

    float* out = (float*)d_out;

    int P = (n + S_NODES - 1) / S_NODES;
    size_t per_b = (size_t)P * S_NODES * sizeof(float2);
    int Bmax = (per_b > 0) ? (int)(ws_size / per_b) : 0;
    int B = B_TARGET < Bmax ? B_TARGET : Bmax;

    if (B >= 1) {
        int chunk = (((e + B - 1) / B) + 3) & ~3;   // 4-aligned chunk per block
        scan_kernel<<<P * B, SCAN_THREADS, 0, stream>>>(
            x, (const int4*)src, (const int4*)dst, src, dst,
            (float2*)d_ws, e, n, B, chunk);
        int threads = 256;
        reduce_kernel<<<(n + threads - 1) / threads, threads, 0, stream>>>(
            (const float2*)d_ws, v, (float2*)out, n, B);
    } else {
        // workspace too small: fall back to direct-atomic path
        int threads = 256;
        init_out_kernel<<<(n + threads - 1) / threads, threads, 0, stream>>>(
            v, (float2*)out, n);
        int e4 = e / 4;
        int blocks = (e4 + threads - 1) / threads;
        if (blocks < 1) blocks = 1;
        edge_kernel_atomic<<<blocks, threads, 0, stream>>>(
            x, (const int4*)src, (const int4*)dst, src, dst, out, e4, e);
    }
}

// Round 3
// 128.427 us; speedup vs baseline: 3.0768x; 1.0402x over previous
//
#include <hip/hip_runtime.h>

#define GAMMA 0.1f
#define EPS_F 1e-12f

// ---- partition-scan configuration ----
// 20000 nodes/partition * sizeof(float2) = 160000 B LDS (gfx950 has 160 KiB/CU)
#define S_NODES 20000
#define SCAN_THREADS 1024
#define B_TARGET 51   // chunks per partition; P=5 -> grid 255 blocks (~1/CU)

// process one edge into the LDS accumulator if dst falls in [lo,hi)
#define EDGE(dd, ss) do {                                        \
    int d_ = (dd);                                               \
    if (d_ >= lo && d_ < hi) {                                   \
        float2 xs = x[(ss)];                                     \
        float2 xd = x[d_];                                       \
        float dx = xd.x - xs.x;                                  \
        float dy = xd.y - xs.y;                                  \
        float r = sqrtf(dx * dx + dy * dy);                      \
        float sc = -2.0f * (r - 1.0f) / fmaxf(r, EPS_F);         \
        atomicAdd(&acc[d_ - lo].x, sc * dx);                     \
        atomicAdd(&acc[d_ - lo].y, sc * dy);                     \
    }                                                            \
} while (0)

__global__ __launch_bounds__(SCAN_THREADS, 1)
void scan_kernel(const float2* __restrict__ x,
                 const int4* __restrict__ src4,
                 const int4* __restrict__ dst4,
                 const int* __restrict__ src,
                 const int* __restrict__ dst,
                 float2* __restrict__ ws,
                 int e, int n, int B, int chunk) {
    __shared__ float2 acc[S_NODES];
    int p = blockIdx.x / B;
    int b = blockIdx.x - p * B;
    int lo = p * S_NODES;
    int hi = min(lo + S_NODES, n);
    int tid = threadIdx.x;

    for (int i = tid; i < S_NODES; i += SCAN_THREADS)
        acc[i] = make_float2(0.f, 0.f);
    __syncthreads();

    int estart = b * chunk;
    int eend = min(estart + chunk, e);
    if (estart < eend) {
        int nvec = (eend - estart) >> 2;           // int4 groups (estart is 4-aligned)
        const int4* d4p = dst4 + (estart >> 2);
        const int4* s4p = src4 + (estart >> 2);
        // two contiguous half-streams -> 2 independent int4-pair loads in
        // flight per thread per iteration (latency hiding, both coalesced)
        int nvec2 = nvec >> 1;
        for (int i = tid; i < nvec2; i += SCAN_THREADS) {
            int4 da = d4p[i];
            int4 sa = s4p[i];
            int4 db = d4p[i + nvec2];
            int4 sb = s4p[i + nvec2];
            EDGE(da.x, sa.x);
            EDGE(da.y, sa.y);
            EDGE(da.z, sa.z);
            EDGE(da.w, sa.w);
            EDGE(db.x, sb.x);
            EDGE(db.y, sb.y);
            EDGE(db.z, sb.z);
            EDGE(db.w, sb.w);
        }
        // odd leftover int4 group
        for (int i = (nvec2 << 1) + tid; i < nvec; i += SCAN_THREADS) {
            int4 d4 = d4p[i];
            int4 s4 = s4p[i];
            EDGE(d4.x, s4.x);
            EDGE(d4.y, s4.y);
            EDGE(d4.z, s4.z);
            EDGE(d4.w, s4.w);
        }
        // scalar tail (eend-estart not multiple of 4)
        for (int i = estart + (nvec << 2) + tid; i < eend; i += SCAN_THREADS)
            EDGE(dst[i], src[i]);
    }
    __syncthreads();

    // flush partition partial to workspace (plain coalesced stores)
    float2* wsb = ws + (size_t)blockIdx.x * S_NODES;
    for (int i = tid; i < S_NODES; i += SCAN_THREADS)
        wsb[i] = acc[i];
}

__global__ __launch_bounds__(256)
void reduce_kernel(const float2* __restrict__ ws,
                   const float2* __restrict__ v,
                   float2* __restrict__ out,
                   int n, int B) {
    int i = blockIdx.x * blockDim.x + threadIdx.x;
    if (i >= n) return;
    int p = i / S_NODES;
    int loc = i - p * S_NODES;
    const float2* base = ws + ((size_t)(p * B) * S_NODES + loc);
    // 8 independent loads in flight per iteration (was a 1-deep chain at
    // VGPR_Count=4 -> fully latency-serialized, ~70us)
    float sx0 = 0.f, sy0 = 0.f, sx1 = 0.f, sy1 = 0.f;
    float sx2 = 0.f, sy2 = 0.f, sx3 = 0.f, sy3 = 0.f;
    int b = 0;
    for (; b + 8 <= B; b += 8) {
        float2 t0 = base[(size_t)(b + 0) * S_NODES];
        float2 t1 = base[(size_t)(b + 1) * S_NODES];
        float2 t2 = base[(size_t)(b + 2) * S_NODES];
        float2 t3 = base[(size_t)(b + 3) * S_NODES];
        float2 t4 = base[(size_t)(b + 4) * S_NODES];
        float2 t5 = base[(size_t)(b + 5) * S_NODES];
        float2 t6 = base[(size_t)(b + 6) * S_NODES];
        float2 t7 = base[(size_t)(b + 7) * S_NODES];
        sx0 += t0.x; sy0 += t0.y; sx1 += t1.x; sy1 += t1.y;
        sx2 += t2.x; sy2 += t2.y; sx3 += t3.x; sy3 += t3.y;
        sx0 += t4.x; sy0 += t4.y; sx1 += t5.x; sy1 += t5.y;
        sx2 += t6.x; sy2 += t6.y; sx3 += t7.x; sy3 += t7.y;
    }
    for (; b < B; ++b) {
        float2 t = base[(size_t)b * S_NODES];
        sx0 += t.x; sy0 += t.y;
    }
    float sx = (sx0 + sx1) + (sx2 + sx3);
    float sy = (sy0 + sy1) + (sy2 + sy3);
    float2 vi = v[i];
    out[i] = make_float2(sx - GAMMA * vi.x, sy - GAMMA * vi.y);
}

// ---------- fallback path (global atomics) if ws too small ----------
__global__ void init_out_kernel(const float2* __restrict__ v,
                                float2* __restrict__ out, int n) {
    int i = blockIdx.x * blockDim.x + threadIdx.x;
    if (i < n) {
        float2 vi = v[i];
        out[i] = make_float2(-GAMMA * vi.x, -GAMMA * vi.y);
    }
}

__device__ __forceinline__ void do_edge_atomic(const float2* __restrict__ x,
                                               int s, int d,
                                               float* __restrict__ out) {
    float2 xs = x[s];
    float2 xd = x[d];
    float dx = xd.x - xs.x;
    float dy = xd.y - xs.y;
    float r = sqrtf(dx * dx + dy * dy);
    float sc = -2.0f * (r - 1.0f) / fmaxf(r, EPS_F);
    atomicAdd(&out[2 * d], sc * dx);
    atomicAdd(&out[2 * d + 1], sc * dy);
}

__global__ void edge_kernel_atomic(const float2* __restrict__ x,
                                   const int4* __restrict__ src4,
                                   const int4* __restrict__ dst4,
                                   const int* __restrict__ src,
                                   const int* __restrict__ dst,
                                   float* __restrict__ out,
                                   int e4, int e_total) {
    int i = blockIdx.x * blockDim.x + threadIdx.x;
    if (i < e4) {
        int4 s = src4[i];
        int4 d = dst4[i];
        do_edge_atomic(x, s.x, d.x, out);
        do_edge_atomic(x, s.y, d.y, out);
        do_edge_atomic(x, s.z, d.z, out);
        do_edge_atomic(x, s.w, d.w, out);
    }
    if (i == 0) {
        for (int e = e4 * 4; e < e_total; ++e)
            do_edge_atomic(x, src[e], dst[e], out);
    }
}

extern "C" void kernel_launch(void* const* d_in, const int* in_sizes, int n_in,
                              void* d_out, int out_size, void* d_ws, size_t ws_size,
                              hipStream_t stream) {
    const float2* x = (const float2*)d_in[0];   // [N,2] fp32
    const float2* v = (const float2*)d_in[1];   // [N,2] fp32
    const int* src  = (const int*)d_in[2];      // [E] int32
    const int* dst  = (const int*)d_in[3];      // [E] int32

    int n = in_sizes[0] / 2;   // N nodes
    int e = in_sizes[2];       // E edges

    float* out = (float*)d_out;

    int P = (n + S_NODES - 1) / S_NODES;
    size_t per_b = (size_t)P * S_NODES * sizeof(float2);
    int Bmax = (per_b > 0) ? (int)(ws_size / per_b) : 0;
    int B = B_TARGET < Bmax ? B_TARGET : Bmax;

    if (B >= 1) {
        int chunk = (((e + B - 1) / B) + 3) & ~3;   // 4-aligned chunk per block
        scan_kernel<<<P * B, SCAN_THREADS, 0, stream>>>(
            x, (const int4*)src, (const int4*)dst, src, dst,
            (float2*)d_ws, e, n, B, chunk);
        int threads = 256;
        reduce_kernel<<<(n + threads - 1) / threads, threads, 0, stream>>>(
            (const float2*)d_ws, v, (float2*)out, n, B);
    } else {
        // workspace too small: fall back to direct-atomic path
        int threads = 256;
        init_out_kernel<<<(n + threads - 1) / threads, threads, 0, stream>>>(
            v, (float2*)out, n);
        int e4 = e / 4;
        int blocks = (e4 + threads - 1) / threads;
        if (blocks < 1) blocks = 1;
        edge_kernel_atomic<<<blocks, threads, 0, stream>>>(
            x, (const int4*)src, (const int4*)dst, src, dst, out, e4, e);
    }
}